// Round 17
// baseline (185.076 us; speedup 1.0000x reference)
//
#include <hip/hip_runtime.h>
#include <hip/hip_bf16.h>
#include <math.h>

#define NHEADS 8
#define CHVAL 32
#define CAP 256   // per-node edge bucket capacity (Poisson λ=10, max deg ~35)
#define WPB 4     // waves (nodes) per block

// One-pass bucketed CSR: c = atomicAdd(cnt[n]); eid2[n*CAP+c] = e.
__global__ void scatter2_kernel(const int* __restrict__ dst,
                                int* __restrict__ cnt,
                                int* __restrict__ eid2,
                                int E) {
    int e = blockIdx.x * blockDim.x + threadIdx.x;
    if (e < E) {
        int n = dst[e];
        int c = atomicAdd(&cnt[n], 1);
        if (c < CAP) eid2[(size_t)n * CAP + c] = e;
    }
}

// Logits v4 — value-loop-shaped key gather. Empirical rule from R10-R16:
// gathers where each lane consumes 64B of a granule via 4 loads run ~2x
// slower (~110us) than the node_kernel value loop where 32 lanes spread the
// granule at 16B/lane (~55us), at identical volume/grid. So: lane (half,l)
// reads ONE float4 of the edge's key (l<8 -> key0[e*8+l], else
// key1[e*24+(l-8)]); partial dot vs the matching q float4 (loaded once per
// node); per-wave LDS slice reduces the 4 partials of each head; lanes l<8
// store 32B/edge, CSR-slot-ordered. 2 edges in flight (half), eids via
// coalesced prefetch + register __shfl broadcast (proven R16 pattern).
__global__ void __launch_bounds__(64 * WPB)
logits_v4_kernel(const float4* __restrict__ key0,   // [E*8]  float4
                 const float4* __restrict__ key1,   // [E*24] float4
                 const float4* __restrict__ q0,     // [N*8]  float4
                 const float4* __restrict__ q1,     // [N*24] float4
                 const int* __restrict__ cnt,       // [N]
                 const int* __restrict__ eid2,      // [N*CAP]
                 float* __restrict__ logits,        // [N*CAP*8] CSR slots
                 int N) {
    __shared__ float part_sh[WPB][2][32];

    int wv = threadIdx.x >> 6;
    int t  = threadIdx.x & 63;
    int n  = blockIdx.x * WPB + wv;
    if (n >= N) return;

    int deg = min(cnt[n], CAP);
    if (deg == 0) return;                       // node_kernel stores zeros

    const float SCALE = 0.08838834764831845f;   // 1/sqrt(128)
    int half = t >> 5;
    int l = t & 31;

    const int* eidp = eid2 + (size_t)n * CAP;
    float* lbase = logits + (size_t)n * CAP * 8;

    // q float4 for this lane's position (halves duplicate -> L1 hit)
    float4 ql = (l < 8) ? q0[(size_t)n * 8 + l]
                        : q1[(size_t)n * 24 + (l - 8)];

    // coalesced eid prefetch for slots < 64 (deg>64 never occurs for λ=10,
    // but the fallback path keeps it correct)
    int myeid = (t < deg) ? eidp[t] : 0;

    for (int base = 0; base < deg; base += 64) {
        int clen = min(64, deg - base);
        for (int ii = half; ii < clen; ii += 2) {
            int e = (base == 0) ? __shfl(myeid, ii, 64)
                                : eidp[base + ii];
            float4 kl = (l < 8) ? key0[(size_t)e * 8 + l]
                                : key1[(size_t)e * 24 + (l - 8)];
            float p = kl.x * ql.x + kl.y * ql.y + kl.z * ql.z + kl.w * ql.w;
            part_sh[wv][half][l] = p;
            __builtin_amdgcn_wave_barrier();    // DS in-order per wave
            if (l < 8) {
                float lg = p
                         + part_sh[wv][half][8  + 3 * l]
                         + part_sh[wv][half][9  + 3 * l]
                         + part_sh[wv][half][10 + 3 * l];
                lbase[(size_t)(base + ii) * 8 + l] = lg * SCALE;
            }
            __builtin_amdgcn_wave_barrier();    // before next overwrite
        }
    }
}

// One WAVE (64 lanes) per node; WPB waves per block, fully independent
// (disjoint LDS slices, no s_barrier). R6-verified body; logits are
// CSR-slot-ordered so lane t reads lbase[t*8] -> one contiguous 2KB wave
// segment. Values gathered via eid2. Do NOT hand-unroll the value loop
// (R8/R9 regression) and do NOT load offsets as int2 (4B align).
__global__ void __launch_bounds__(64 * WPB)
node_kernel(const float* __restrict__ logits,    // [N*CAP*8] CSR slots
            const float4* __restrict__ value0,   // [E*8]  float4
            const float4* __restrict__ value1,   // [E*24] float4
            const int* __restrict__ cnt,         // [N]
            const int* __restrict__ eid2,        // [N*CAP]
            float4* __restrict__ out0,           // [N*8]  float4
            float4* __restrict__ out1,           // [N*24] float4
            int N) {
    __shared__ float w_sh[WPB][64][9];           // padded: stride 9 banks

    int wv = threadIdx.x >> 6;
    int t  = threadIdx.x & 63;
    int n  = blockIdx.x * WPB + wv;
    if (n >= N) return;

    const int* eidp = eid2 + (size_t)n * CAP;
    const float* lbase = logits + (size_t)n * CAP * 8;
    int deg = min(cnt[n], CAP);

    if (deg == 0) {
        float4 z = {0.f, 0.f, 0.f, 0.f};
        if (t < 8) out0[(size_t)n * 8 + t] = z;
        else if (t < 32) out1[(size_t)n * 24 + (t - 8)] = z;
        return;
    }

    // chunk-0 logits: lane t -> slot t (32B contiguous, coalesced wave read)
    int myeid = -1;
    float lg[8];
    if (t < deg) {
        myeid = eidp[t];
        const float4* lp = (const float4*)(lbase + (size_t)t * 8);
        float4 a = lp[0], b = lp[1];
        lg[0] = a.x; lg[1] = a.y; lg[2] = a.z; lg[3] = a.w;
        lg[4] = b.x; lg[5] = b.y; lg[6] = b.z; lg[7] = b.w;
    } else {
#pragma unroll
        for (int k = 0; k < 8; ++k) lg[k] = -INFINITY;
    }

    // per-head max (running over rare extra chunks)
    float mx[8];
#pragma unroll
    for (int k = 0; k < 8; ++k) mx[k] = lg[k];
    for (int base = 64; base < deg; base += 64) {       // rare: deg > 64
        if (base + t < deg) {
            const float4* lp = (const float4*)(lbase + (size_t)(base + t) * 8);
            float4 a = lp[0], b = lp[1];
            float tt[8] = {a.x, a.y, a.z, a.w, b.x, b.y, b.z, b.w};
#pragma unroll
            for (int k = 0; k < 8; ++k) mx[k] = fmaxf(mx[k], tt[k]);
        }
    }
#pragma unroll
    for (int k = 0; k < 8; ++k)
        for (int off = 32; off; off >>= 1)
            mx[k] = fmaxf(mx[k], __shfl_xor(mx[k], off, 64));

    // per-head sum of exp (exp(-inf - m) = 0 handles inactive lanes)
    float ex0[8], sm[8];
#pragma unroll
    for (int k = 0; k < 8; ++k) { ex0[k] = __expf(lg[k] - mx[k]); sm[k] = ex0[k]; }
    for (int base = 64; base < deg; base += 64) {       // rare
        if (base + t < deg) {
            const float4* lp = (const float4*)(lbase + (size_t)(base + t) * 8);
            float4 a = lp[0], b = lp[1];
            float tt[8] = {a.x, a.y, a.z, a.w, b.x, b.y, b.z, b.w};
#pragma unroll
            for (int k = 0; k < 8; ++k) sm[k] += __expf(tt[k] - mx[k]);
        }
    }
#pragma unroll
    for (int k = 0; k < 8; ++k)
        for (int off = 32; off; off >>= 1)
            sm[k] += __shfl_xor(sm[k], off, 64);
    float inv[8];
#pragma unroll
    for (int k = 0; k < 8; ++k) inv[k] = 1.0f / sm[k];

    // value accumulation: each 32-lane half owns alternate edges; lane's
    // float4 is a single-head slice (myh) of value0/value1.
    int half = t >> 5;
    int l = t & 31;
    int myh = (l < 8) ? l : ((l - 8) / 3);
    float4 acc = {0.f, 0.f, 0.f, 0.f};

    for (int base = 0; base < deg; base += 64) {
        int clen = min(64, deg - base);
        if (base == 0) {
            if (t < clen) {
#pragma unroll
                for (int k = 0; k < 8; ++k) w_sh[wv][t][k] = ex0[k] * inv[k];
            }
        } else {                                        // rare
            if (base + t < deg) {
                const float4* lp = (const float4*)(lbase + (size_t)(base + t) * 8);
                float4 a = lp[0], b = lp[1];
                float tt[8] = {a.x, a.y, a.z, a.w, b.x, b.y, b.z, b.w};
#pragma unroll
                for (int k = 0; k < 8; ++k)
                    w_sh[wv][t][k] = __expf(tt[k] - mx[k]) * inv[k];
            }
        }
        __builtin_amdgcn_wave_barrier();  // compiler fence: DS pipe is in-order per wave

        for (int ii = half; ii < clen; ii += 2) {
            int e = (base == 0) ? __shfl(myeid, ii, 64)
                                : eidp[base + ii];
            float w = w_sh[wv][ii][myh];
            float4 v = (l < 8) ? value0[(size_t)e * 8 + l]
                               : value1[(size_t)e * 24 + (l - 8)];
            acc.x += w * v.x;
            acc.y += w * v.y;
            acc.z += w * v.z;
            acc.w += w * v.w;
        }
        __builtin_amdgcn_wave_barrier();
    }

    // cross-half reduce, lanes 0-31 store
    acc.x += __shfl_xor(acc.x, 32, 64);
    acc.y += __shfl_xor(acc.y, 32, 64);
    acc.z += __shfl_xor(acc.z, 32, 64);
    acc.w += __shfl_xor(acc.w, 32, 64);
    if (t < 8)       out0[(size_t)n * 8 + l] = acc;
    else if (t < 32) out1[(size_t)n * 24 + (l - 8)] = acc;
}

extern "C" void kernel_launch(void* const* d_in, const int* in_sizes, int n_in,
                              void* d_out, int out_size, void* d_ws, size_t ws_size,
                              hipStream_t stream) {
    const float* key0   = (const float*)d_in[0];
    const float* key1   = (const float*)d_in[1];
    const float* value0 = (const float*)d_in[2];
    const float* value1 = (const float*)d_in[3];
    const float* query0 = (const float*)d_in[4];
    const float* query1 = (const float*)d_in[5];
    const int*   dst    = (const int*)d_in[6];

    int E = in_sizes[0] / CHVAL;   // 500000
    int N = in_sizes[4] / CHVAL;   // 50000

    // workspace layout (4-byte elements):
    //   logits [N*CAP*8] = 409.6 MB (CSR-slot order, only deg slots touched)
    //   cnt    [N]
    //   eid2   [N*CAP]   = 51.2 MB
    float* logits = (float*)d_ws;
    int*   cnt    = (int*)(logits + (size_t)N * CAP * 8);
    int*   eid2   = cnt + N;

    float* out0 = (float*)d_out;             // N*32
    float* out1 = out0 + (size_t)N * 32;     // N*96

    hipMemsetAsync(cnt, 0, (size_t)N * sizeof(int), stream);

    int blk = 256;
    scatter2_kernel<<<(E + blk - 1) / blk, blk, 0, stream>>>(dst, cnt, eid2, E);

    int nnb = (N + WPB - 1) / WPB;
    logits_v4_kernel<<<nnb, 64 * WPB, 0, stream>>>(
        (const float4*)key0, (const float4*)key1,
        (const float4*)query0, (const float4*)query1,
        cnt, eid2, logits, N);

    node_kernel<<<nnb, 64 * WPB, 0, stream>>>(logits,
                                              (const float4*)value0,
                                              (const float4*)value1,
                                              cnt, eid2,
                                              (float4*)out0, (float4*)out1, N);
}

// Round 18
// 184.885 us; speedup vs baseline: 1.0010x; 1.0010x over previous
//
#include <hip/hip_runtime.h>
#include <hip/hip_bf16.h>
#include <math.h>

#define NHEADS 8
#define CHVAL 32
#define CAP 256   // per-node edge bucket capacity (Poisson λ=10, max deg ~35)
#define WPB 4     // waves (nodes) per block

// One-pass bucketed CSR: c = atomicAdd(cnt[n]); eid2[n*CAP+c] = e.
__global__ void scatter2_kernel(const int* __restrict__ dst,
                                int* __restrict__ cnt,
                                int* __restrict__ eid2,
                                int E) {
    int e = blockIdx.x * blockDim.x + threadIdx.x;
    if (e < E) {
        int n = dst[e];
        int c = atomicAdd(&cnt[n], 1);
        if (c < CAP) eid2[(size_t)n * CAP + c] = e;
    }
}

// Logits v5 — value-loop-shaped key gather, FENCE-FREE (v4 minus the
// serializing barriers). Lane (half,l) reads ONE float4 of the edge's key
// (l<8 -> key0[e*8+l] else key1[e*24+(l-8)]); partial dot vs the matching
// register-resident q float4; the 4 partials of head h (lanes h, 8+3h,
// 9+3h, 10+3h within the half) combine via three __shfl (ds_bpermute — no
// LDS, no wave_barrier), so consecutive edges' loads pipeline freely like
// node_kernel's value loop. 2 edges in flight (half split), eids via
// coalesced prefetch + register __shfl broadcast. CSR-slot-ordered output.
__global__ void __launch_bounds__(64 * WPB)
logits_v5_kernel(const float4* __restrict__ key0,   // [E*8]  float4
                 const float4* __restrict__ key1,   // [E*24] float4
                 const float4* __restrict__ q0,     // [N*8]  float4
                 const float4* __restrict__ q1,     // [N*24] float4
                 const int* __restrict__ cnt,       // [N]
                 const int* __restrict__ eid2,      // [N*CAP]
                 float* __restrict__ logits,        // [N*CAP*8] CSR slots
                 int N) {
    int wv = threadIdx.x >> 6;
    int t  = threadIdx.x & 63;
    int n  = blockIdx.x * WPB + wv;
    if (n >= N) return;

    int deg = min(cnt[n], CAP);
    if (deg == 0) return;                       // node_kernel stores zeros

    const float SCALE = 0.08838834764831845f;   // 1/sqrt(128)
    int half = t >> 5;
    int l = t & 31;
    int hbase = half << 5;                      // first lane of my half

    const int* eidp = eid2 + (size_t)n * CAP;
    float* lbase = logits + (size_t)n * CAP * 8;

    // q float4 for this lane's position (halves duplicate -> L1 hit)
    float4 ql = (l < 8) ? q0[(size_t)n * 8 + l]
                        : q1[(size_t)n * 24 + (l - 8)];

    // shfl source lanes for head-l partial combine (only used when l < 8)
    int src1 = hbase + 8 + 3 * l;
    int src2 = hbase + 9 + 3 * l;
    int src3 = hbase + 10 + 3 * l;

    // coalesced eid prefetch for slots < 64 (deg>64 never occurs for λ=10;
    // fallback below keeps it correct)
    int myeid = (t < deg) ? eidp[t] : 0;

    for (int base = 0; base < deg; base += 64) {
        int clen = min(64, deg - base);
        for (int ii = half; ii < clen; ii += 2) {
            int e = (base == 0) ? __shfl(myeid, ii, 64)
                                : eidp[base + ii];
            float4 kl = (l < 8) ? key0[(size_t)e * 8 + l]
                                : key1[(size_t)e * 24 + (l - 8)];
            float p = kl.x * ql.x + kl.y * ql.y + kl.z * ql.z + kl.w * ql.w;
            // barrier-free combine: head l (l<8) sums lanes {l,8+3l,9+3l,10+3l}
            float p1 = __shfl(p, src1, 64);
            float p2 = __shfl(p, src2, 64);
            float p3 = __shfl(p, src3, 64);
            if (l < 8)
                lbase[(size_t)(base + ii) * 8 + l] = (p + p1 + p2 + p3) * SCALE;
        }
    }
}

// One WAVE (64 lanes) per node; WPB waves per block, fully independent
// (disjoint LDS slices, no s_barrier). R6-verified body; logits are
// CSR-slot-ordered so lane t reads lbase[t*8] -> one contiguous 2KB wave
// segment. Values gathered via eid2. Do NOT hand-unroll the value loop
// (R8/R9 regression) and do NOT load offsets as int2 (4B align).
__global__ void __launch_bounds__(64 * WPB)
node_kernel(const float* __restrict__ logits,    // [N*CAP*8] CSR slots
            const float4* __restrict__ value0,   // [E*8]  float4
            const float4* __restrict__ value1,   // [E*24] float4
            const int* __restrict__ cnt,         // [N]
            const int* __restrict__ eid2,        // [N*CAP]
            float4* __restrict__ out0,           // [N*8]  float4
            float4* __restrict__ out1,           // [N*24] float4
            int N) {
    __shared__ float w_sh[WPB][64][9];           // padded: stride 9 banks

    int wv = threadIdx.x >> 6;
    int t  = threadIdx.x & 63;
    int n  = blockIdx.x * WPB + wv;
    if (n >= N) return;

    const int* eidp = eid2 + (size_t)n * CAP;
    const float* lbase = logits + (size_t)n * CAP * 8;
    int deg = min(cnt[n], CAP);

    if (deg == 0) {
        float4 z = {0.f, 0.f, 0.f, 0.f};
        if (t < 8) out0[(size_t)n * 8 + t] = z;
        else if (t < 32) out1[(size_t)n * 24 + (t - 8)] = z;
        return;
    }

    // chunk-0 logits: lane t -> slot t (32B contiguous, coalesced wave read)
    int myeid = -1;
    float lg[8];
    if (t < deg) {
        myeid = eidp[t];
        const float4* lp = (const float4*)(lbase + (size_t)t * 8);
        float4 a = lp[0], b = lp[1];
        lg[0] = a.x; lg[1] = a.y; lg[2] = a.z; lg[3] = a.w;
        lg[4] = b.x; lg[5] = b.y; lg[6] = b.z; lg[7] = b.w;
    } else {
#pragma unroll
        for (int k = 0; k < 8; ++k) lg[k] = -INFINITY;
    }

    // per-head max (running over rare extra chunks)
    float mx[8];
#pragma unroll
    for (int k = 0; k < 8; ++k) mx[k] = lg[k];
    for (int base = 64; base < deg; base += 64) {       // rare: deg > 64
        if (base + t < deg) {
            const float4* lp = (const float4*)(lbase + (size_t)(base + t) * 8);
            float4 a = lp[0], b = lp[1];
            float tt[8] = {a.x, a.y, a.z, a.w, b.x, b.y, b.z, b.w};
#pragma unroll
            for (int k = 0; k < 8; ++k) mx[k] = fmaxf(mx[k], tt[k]);
        }
    }
#pragma unroll
    for (int k = 0; k < 8; ++k)
        for (int off = 32; off; off >>= 1)
            mx[k] = fmaxf(mx[k], __shfl_xor(mx[k], off, 64));

    // per-head sum of exp (exp(-inf - m) = 0 handles inactive lanes)
    float ex0[8], sm[8];
#pragma unroll
    for (int k = 0; k < 8; ++k) { ex0[k] = __expf(lg[k] - mx[k]); sm[k] = ex0[k]; }
    for (int base = 64; base < deg; base += 64) {       // rare
        if (base + t < deg) {
            const float4* lp = (const float4*)(lbase + (size_t)(base + t) * 8);
            float4 a = lp[0], b = lp[1];
            float tt[8] = {a.x, a.y, a.z, a.w, b.x, b.y, b.z, b.w};
#pragma unroll
            for (int k = 0; k < 8; ++k) sm[k] += __expf(tt[k] - mx[k]);
        }
    }
#pragma unroll
    for (int k = 0; k < 8; ++k)
        for (int off = 32; off; off >>= 1)
            sm[k] += __shfl_xor(sm[k], off, 64);
    float inv[8];
#pragma unroll
    for (int k = 0; k < 8; ++k) inv[k] = 1.0f / sm[k];

    // value accumulation: each 32-lane half owns alternate edges; lane's
    // float4 is a single-head slice (myh) of value0/value1.
    int half = t >> 5;
    int l = t & 31;
    int myh = (l < 8) ? l : ((l - 8) / 3);
    float4 acc = {0.f, 0.f, 0.f, 0.f};

    for (int base = 0; base < deg; base += 64) {
        int clen = min(64, deg - base);
        if (base == 0) {
            if (t < clen) {
#pragma unroll
                for (int k = 0; k < 8; ++k) w_sh[wv][t][k] = ex0[k] * inv[k];
            }
        } else {                                        // rare
            if (base + t < deg) {
                const float4* lp = (const float4*)(lbase + (size_t)(base + t) * 8);
                float4 a = lp[0], b = lp[1];
                float tt[8] = {a.x, a.y, a.z, a.w, b.x, b.y, b.z, b.w};
#pragma unroll
                for (int k = 0; k < 8; ++k)
                    w_sh[wv][t][k] = __expf(tt[k] - mx[k]) * inv[k];
            }
        }
        __builtin_amdgcn_wave_barrier();  // compiler fence: DS pipe is in-order per wave

        for (int ii = half; ii < clen; ii += 2) {
            int e = (base == 0) ? __shfl(myeid, ii, 64)
                                : eidp[base + ii];
            float w = w_sh[wv][ii][myh];
            float4 v = (l < 8) ? value0[(size_t)e * 8 + l]
                               : value1[(size_t)e * 24 + (l - 8)];
            acc.x += w * v.x;
            acc.y += w * v.y;
            acc.z += w * v.z;
            acc.w += w * v.w;
        }
        __builtin_amdgcn_wave_barrier();
    }

    // cross-half reduce, lanes 0-31 store
    acc.x += __shfl_xor(acc.x, 32, 64);
    acc.y += __shfl_xor(acc.y, 32, 64);
    acc.z += __shfl_xor(acc.z, 32, 64);
    acc.w += __shfl_xor(acc.w, 32, 64);
    if (t < 8)       out0[(size_t)n * 8 + l] = acc;
    else if (t < 32) out1[(size_t)n * 24 + (l - 8)] = acc;
}

extern "C" void kernel_launch(void* const* d_in, const int* in_sizes, int n_in,
                              void* d_out, int out_size, void* d_ws, size_t ws_size,
                              hipStream_t stream) {
    const float* key0   = (const float*)d_in[0];
    const float* key1   = (const float*)d_in[1];
    const float* value0 = (const float*)d_in[2];
    const float* value1 = (const float*)d_in[3];
    const float* query0 = (const float*)d_in[4];
    const float* query1 = (const float*)d_in[5];
    const int*   dst    = (const int*)d_in[6];

    int E = in_sizes[0] / CHVAL;   // 500000
    int N = in_sizes[4] / CHVAL;   // 50000

    // workspace layout (4-byte elements):
    //   logits [N*CAP*8] = 409.6 MB (CSR-slot order, only deg slots touched)
    //   cnt    [N]
    //   eid2   [N*CAP]   = 51.2 MB
    float* logits = (float*)d_ws;
    int*   cnt    = (int*)(logits + (size_t)N * CAP * 8);
    int*   eid2   = cnt + N;

    float* out0 = (float*)d_out;             // N*32
    float* out1 = out0 + (size_t)N * 32;     // N*96

    hipMemsetAsync(cnt, 0, (size_t)N * sizeof(int), stream);

    int blk = 256;
    scatter2_kernel<<<(E + blk - 1) / blk, blk, 0, stream>>>(dst, cnt, eid2, E);

    int nnb = (N + WPB - 1) / WPB;
    logits_v5_kernel<<<nnb, 64 * WPB, 0, stream>>>(
        (const float4*)key0, (const float4*)key1,
        (const float4*)query0, (const float4*)query1,
        cnt, eid2, logits, N);

    node_kernel<<<nnb, 64 * WPB, 0, stream>>>(logits,
                                              (const float4*)value0,
                                              (const float4*)value1,
                                              cnt, eid2,
                                              (float4*)out0, (float4*)out1, N);
}

// Round 19
// 177.944 us; speedup vs baseline: 1.0401x; 1.0390x over previous
//
#include <hip/hip_runtime.h>
#include <hip/hip_bf16.h>
#include <math.h>

#define NHEADS 8
#define CHVAL 32
#define CAP 256   // per-node edge bucket capacity (Poisson λ=10, max deg ~35)
#define WPB 4     // waves (nodes) per block

// One-pass bucketed CSR: c = atomicAdd(cnt[n]); eid2[n*CAP+c] = e.
__global__ void scatter2_kernel(const int* __restrict__ dst,
                                int* __restrict__ cnt,
                                int* __restrict__ eid2,
                                int E) {
    int e = blockIdx.x * blockDim.x + threadIdx.x;
    if (e < E) {
        int n = dst[e];
        int c = atomicAdd(&cnt[n], 1);
        if (c < CAP) eid2[(size_t)n * CAP + c] = e;
    }
}

// Logits v6 — 16B/lane key gather with loads DECOUPLED from cross-lane ops.
// v5's stall: its per-iteration shfl combine consumed the fresh load, forcing
// vmcnt(0) every edge (one serial HBM latency per edge). v6 fully unrolls a
// 16-slot block with statically-indexed p[8]: phase 1 issues all 8 guarded
// loads back-to-back (only consumer is the lane-local dot), phase 2 runs the
// 24 shfls + 8 guarded stores afterward — one HBM latency per block of 16
// edges instead of per edge. No LDS, no fences, all lanes active at shfls.
__global__ void __launch_bounds__(64 * WPB)
logits_v6_kernel(const float4* __restrict__ key0,   // [E*8]  float4
                 const float4* __restrict__ key1,   // [E*24] float4
                 const float4* __restrict__ q0,     // [N*8]  float4
                 const float4* __restrict__ q1,     // [N*24] float4
                 const int* __restrict__ cnt,       // [N]
                 const int* __restrict__ eid2,      // [N*CAP]
                 float* __restrict__ logits,        // [N*CAP*8] CSR slots
                 int N) {
    int wv = threadIdx.x >> 6;
    int t  = threadIdx.x & 63;
    int n  = blockIdx.x * WPB + wv;
    if (n >= N) return;

    int deg = min(cnt[n], CAP);
    if (deg == 0) return;                       // node_kernel stores zeros

    const float SCALE = 0.08838834764831845f;   // 1/sqrt(128)
    int half = t >> 5;
    int l = t & 31;
    int hbase = half << 5;                      // first lane of my half

    const int* eidp = eid2 + (size_t)n * CAP;
    float* lbase = logits + (size_t)n * CAP * 8;

    // q float4 for this lane's position (halves duplicate -> L1 hit)
    float4 ql = (l < 8) ? q0[(size_t)n * 8 + l]
                        : q1[(size_t)n * 24 + (l - 8)];

    // shfl source lanes for head-l partial combine (only used when l < 8)
    int src1 = hbase + 8 + 3 * l;
    int src2 = hbase + 9 + 3 * l;
    int src3 = hbase + 10 + 3 * l;

    // coalesced eid prefetch (deg<=64 always for this data; guarded anyway)
    int myeid = (t < deg) ? eidp[t] : 0;

    for (int base = 0; base < deg; base += 16) {
        float p[8];
        // phase 1: issue all 8 guarded loads; only lane-local consumers
#pragma unroll
        for (int r = 0; r < 8; ++r) {
            int ii = base + half + 2 * r;       // my half's slot in this block
            int e  = (ii < 64) ? __shfl(myeid, ii, 64)
                               : ((ii < deg) ? eidp[ii] : 0);
            bool act = ii < deg;
            float4 kl;
            if (act) {
                kl = (l < 8) ? key0[(size_t)e * 8 + l]
                             : key1[(size_t)e * 24 + (l - 8)];
            } else {
                kl = make_float4(0.f, 0.f, 0.f, 0.f);
            }
            p[r] = kl.x * ql.x + kl.y * ql.y + kl.z * ql.z + kl.w * ql.w;
        }
        // phase 2: cross-lane combines + stores (loads already in flight/done)
#pragma unroll
        for (int r = 0; r < 8; ++r) {
            int ii = base + half + 2 * r;
            float p1 = __shfl(p[r], src1, 64);
            float p2 = __shfl(p[r], src2, 64);
            float p3 = __shfl(p[r], src3, 64);
            if (l < 8 && ii < deg)
                lbase[(size_t)ii * 8 + l] = (p[r] + p1 + p2 + p3) * SCALE;
        }
    }
}

// One WAVE (64 lanes) per node; WPB waves per block, fully independent
// (disjoint LDS slices, no s_barrier). R6-verified body; logits are
// CSR-slot-ordered so lane t reads lbase[t*8] -> one contiguous 2KB wave
// segment. Values gathered via eid2. Do NOT hand-unroll the value loop
// (R8/R9 regression) and do NOT load offsets as int2 (4B align).
__global__ void __launch_bounds__(64 * WPB)
node_kernel(const float* __restrict__ logits,    // [N*CAP*8] CSR slots
            const float4* __restrict__ value0,   // [E*8]  float4
            const float4* __restrict__ value1,   // [E*24] float4
            const int* __restrict__ cnt,         // [N]
            const int* __restrict__ eid2,        // [N*CAP]
            float4* __restrict__ out0,           // [N*8]  float4
            float4* __restrict__ out1,           // [N*24] float4
            int N) {
    __shared__ float w_sh[WPB][64][9];           // padded: stride 9 banks

    int wv = threadIdx.x >> 6;
    int t  = threadIdx.x & 63;
    int n  = blockIdx.x * WPB + wv;
    if (n >= N) return;

    const int* eidp = eid2 + (size_t)n * CAP;
    const float* lbase = logits + (size_t)n * CAP * 8;
    int deg = min(cnt[n], CAP);

    if (deg == 0) {
        float4 z = {0.f, 0.f, 0.f, 0.f};
        if (t < 8) out0[(size_t)n * 8 + t] = z;
        else if (t < 32) out1[(size_t)n * 24 + (t - 8)] = z;
        return;
    }

    // chunk-0 logits: lane t -> slot t (32B contiguous, coalesced wave read)
    int myeid = -1;
    float lg[8];
    if (t < deg) {
        myeid = eidp[t];
        const float4* lp = (const float4*)(lbase + (size_t)t * 8);
        float4 a = lp[0], b = lp[1];
        lg[0] = a.x; lg[1] = a.y; lg[2] = a.z; lg[3] = a.w;
        lg[4] = b.x; lg[5] = b.y; lg[6] = b.z; lg[7] = b.w;
    } else {
#pragma unroll
        for (int k = 0; k < 8; ++k) lg[k] = -INFINITY;
    }

    // per-head max (running over rare extra chunks)
    float mx[8];
#pragma unroll
    for (int k = 0; k < 8; ++k) mx[k] = lg[k];
    for (int base = 64; base < deg; base += 64) {       // rare: deg > 64
        if (base + t < deg) {
            const float4* lp = (const float4*)(lbase + (size_t)(base + t) * 8);
            float4 a = lp[0], b = lp[1];
            float tt[8] = {a.x, a.y, a.z, a.w, b.x, b.y, b.z, b.w};
#pragma unroll
            for (int k = 0; k < 8; ++k) mx[k] = fmaxf(mx[k], tt[k]);
        }
    }
#pragma unroll
    for (int k = 0; k < 8; ++k)
        for (int off = 32; off; off >>= 1)
            mx[k] = fmaxf(mx[k], __shfl_xor(mx[k], off, 64));

    // per-head sum of exp (exp(-inf - m) = 0 handles inactive lanes)
    float ex0[8], sm[8];
#pragma unroll
    for (int k = 0; k < 8; ++k) { ex0[k] = __expf(lg[k] - mx[k]); sm[k] = ex0[k]; }
    for (int base = 64; base < deg; base += 64) {       // rare
        if (base + t < deg) {
            const float4* lp = (const float4*)(lbase + (size_t)(base + t) * 8);
            float4 a = lp[0], b = lp[1];
            float tt[8] = {a.x, a.y, a.z, a.w, b.x, b.y, b.z, b.w};
#pragma unroll
            for (int k = 0; k < 8; ++k) sm[k] += __expf(tt[k] - mx[k]);
        }
    }
#pragma unroll
    for (int k = 0; k < 8; ++k)
        for (int off = 32; off; off >>= 1)
            sm[k] += __shfl_xor(sm[k], off, 64);
    float inv[8];
#pragma unroll
    for (int k = 0; k < 8; ++k) inv[k] = 1.0f / sm[k];

    // value accumulation: each 32-lane half owns alternate edges; lane's
    // float4 is a single-head slice (myh) of value0/value1.
    int half = t >> 5;
    int l = t & 31;
    int myh = (l < 8) ? l : ((l - 8) / 3);
    float4 acc = {0.f, 0.f, 0.f, 0.f};

    for (int base = 0; base < deg; base += 64) {
        int clen = min(64, deg - base);
        if (base == 0) {
            if (t < clen) {
#pragma unroll
                for (int k = 0; k < 8; ++k) w_sh[wv][t][k] = ex0[k] * inv[k];
            }
        } else {                                        // rare
            if (base + t < deg) {
                const float4* lp = (const float4*)(lbase + (size_t)(base + t) * 8);
                float4 a = lp[0], b = lp[1];
                float tt[8] = {a.x, a.y, a.z, a.w, b.x, b.y, b.z, b.w};
#pragma unroll
                for (int k = 0; k < 8; ++k)
                    w_sh[wv][t][k] = __expf(tt[k] - mx[k]) * inv[k];
            }
        }
        __builtin_amdgcn_wave_barrier();  // compiler fence: DS pipe is in-order per wave

        for (int ii = half; ii < clen; ii += 2) {
            int e = (base == 0) ? __shfl(myeid, ii, 64)
                                : eidp[base + ii];
            float w = w_sh[wv][ii][myh];
            float4 v = (l < 8) ? value0[(size_t)e * 8 + l]
                               : value1[(size_t)e * 24 + (l - 8)];
            acc.x += w * v.x;
            acc.y += w * v.y;
            acc.z += w * v.z;
            acc.w += w * v.w;
        }
        __builtin_amdgcn_wave_barrier();
    }

    // cross-half reduce, lanes 0-31 store
    acc.x += __shfl_xor(acc.x, 32, 64);
    acc.y += __shfl_xor(acc.y, 32, 64);
    acc.z += __shfl_xor(acc.z, 32, 64);
    acc.w += __shfl_xor(acc.w, 32, 64);
    if (t < 8)       out0[(size_t)n * 8 + l] = acc;
    else if (t < 32) out1[(size_t)n * 24 + (l - 8)] = acc;
}

extern "C" void kernel_launch(void* const* d_in, const int* in_sizes, int n_in,
                              void* d_out, int out_size, void* d_ws, size_t ws_size,
                              hipStream_t stream) {
    const float* key0   = (const float*)d_in[0];
    const float* key1   = (const float*)d_in[1];
    const float* value0 = (const float*)d_in[2];
    const float* value1 = (const float*)d_in[3];
    const float* query0 = (const float*)d_in[4];
    const float* query1 = (const float*)d_in[5];
    const int*   dst    = (const int*)d_in[6];

    int E = in_sizes[0] / CHVAL;   // 500000
    int N = in_sizes[4] / CHVAL;   // 50000

    // workspace layout (4-byte elements):
    //   logits [N*CAP*8] = 409.6 MB (CSR-slot order, only deg slots touched)
    //   cnt    [N]
    //   eid2   [N*CAP]   = 51.2 MB
    float* logits = (float*)d_ws;
    int*   cnt    = (int*)(logits + (size_t)N * CAP * 8);
    int*   eid2   = cnt + N;

    float* out0 = (float*)d_out;             // N*32
    float* out1 = out0 + (size_t)N * 32;     // N*96

    hipMemsetAsync(cnt, 0, (size_t)N * sizeof(int), stream);

    int blk = 256;
    scatter2_kernel<<<(E + blk - 1) / blk, blk, 0, stream>>>(dst, cnt, eid2, E);

    int nnb = (N + WPB - 1) / WPB;
    logits_v6_kernel<<<nnb, 64 * WPB, 0, stream>>>(
        (const float4*)key0, (const float4*)key1,
        (const float4*)query0, (const float4*)query1,
        cnt, eid2, logits, N);

    node_kernel<<<nnb, 64 * WPB, 0, stream>>>(logits,
                                              (const float4*)value0,
                                              (const float4*)value1,
                                              cnt, eid2,
                                              (float4*)out0, (float4*)out1, N);
}

// Round 20
// 173.519 us; speedup vs baseline: 1.0666x; 1.0255x over previous
//
#include <hip/hip_runtime.h>
#include <hip/hip_bf16.h>
#include <math.h>

#define NHEADS 8
#define CHVAL 32
#define CAP 256   // per-node edge bucket capacity (Poisson λ=10, max deg ~35)
#define WPB 4     // waves (nodes) per block

// One-pass bucketed CSR: c = atomicAdd(cnt[n]); eid2[n*CAP+c] = e.
__global__ void scatter2_kernel(const int* __restrict__ dst,
                                int* __restrict__ cnt,
                                int* __restrict__ eid2,
                                int E) {
    int e = blockIdx.x * blockDim.x + threadIdx.x;
    if (e < E) {
        int n = dst[e];
        int c = atomicAdd(&cnt[n], 1);
        if (c < CAP) eid2[(size_t)n * CAP + c] = e;
    }
}

// Wave-per-node CSR logits (best-measured variant, R16). Edge-ids prefetched
// in ONE coalesced load (lane t -> eidp[t]) and broadcast via register
// __shfl; each iteration covers 16 slots (2 guarded chains per lane). q is
// register-resident per node. Logits written CSR-slot-ordered. NOTE (R10-R19
// ledger): eight structural variants of this phase all measure 107-118us —
// the 512B-granule key gather is the hardware wall, not the code shape.
__global__ void __launch_bounds__(64 * WPB)
logits_csr3_kernel(const float4* __restrict__ key0,   // [E*8]  float4
                   const float4* __restrict__ key1,   // [E*24] float4
                   const float4* __restrict__ q0,     // [N*8]  float4
                   const float4* __restrict__ q1,     // [N*24] float4
                   const int* __restrict__ cnt,       // [N]
                   const int* __restrict__ eid2,      // [N*CAP]
                   float* __restrict__ logits,        // [N*CAP*8] CSR slots
                   int N) {
    int wv = threadIdx.x >> 6;
    int t  = threadIdx.x & 63;
    int n  = blockIdx.x * WPB + wv;
    if (n >= N) return;

    int deg = min(cnt[n], CAP);
    if (deg == 0) return;                       // node_kernel stores zeros

    const float SCALE = 0.08838834764831845f;   // 1/sqrt(128)
    int s = t >> 3;                             // edge sub-slot (0..7)
    int h = t & 7;                              // head

    const int* eidp = eid2 + (size_t)n * CAP;
    float* lbase = logits + (size_t)n * CAP * 8;

    // this node's head-h query slice (64B), register-resident
    float4 qa  = q0[(size_t)n * 8 + h];
    float4 qb0 = q1[(size_t)n * 24 + 3 * h + 0];
    float4 qb1 = q1[(size_t)n * 24 + 3 * h + 1];
    float4 qb2 = q1[(size_t)n * 24 + 3 * h + 2];

    // one coalesced eid prefetch; slots >=64 (never for this data) fall back
    int myeid = (t < deg) ? eidp[t] : 0;

    for (int base = 0; base < deg; base += 16) {
        int slotA = base + s;
        int slotB = base + 8 + s;
        int eA = __shfl(myeid, slotA & 63, 64);   // register broadcast
        int eB = __shfl(myeid, slotB & 63, 64);

        if (slotA < deg) {
            if (slotA >= 64) eA = eidp[slotA];    // rare fallback
            float4 ka  = key0[(size_t)eA * 8 + h];
            float4 kb0 = key1[(size_t)eA * 24 + 3 * h + 0];
            float4 kb1 = key1[(size_t)eA * 24 + 3 * h + 1];
            float4 kb2 = key1[(size_t)eA * 24 + 3 * h + 2];
            float d = ka.x * qa.x + ka.y * qa.y + ka.z * qa.z + ka.w * qa.w
                    + kb0.x * qb0.x + kb0.y * qb0.y + kb0.z * qb0.z + kb0.w * qb0.w
                    + kb1.x * qb1.x + kb1.y * qb1.y + kb1.z * qb1.z + kb1.w * qb1.w
                    + kb2.x * qb2.x + kb2.y * qb2.y + kb2.z * qb2.z + kb2.w * qb2.w;
            lbase[(size_t)slotA * 8 + h] = d * SCALE;
        }
        if (slotB < deg) {
            if (slotB >= 64) eB = eidp[slotB];    // rare fallback
            float4 ka  = key0[(size_t)eB * 8 + h];
            float4 kb0 = key1[(size_t)eB * 24 + 3 * h + 0];
            float4 kb1 = key1[(size_t)eB * 24 + 3 * h + 1];
            float4 kb2 = key1[(size_t)eB * 24 + 3 * h + 2];
            float d = ka.x * qa.x + ka.y * qa.y + ka.z * qa.z + ka.w * qa.w
                    + kb0.x * qb0.x + kb0.y * qb0.y + kb0.z * qb0.z + kb0.w * qb0.w
                    + kb1.x * qb1.x + kb1.y * qb1.y + kb1.z * qb1.z + kb1.w * qb1.w
                    + kb2.x * qb2.x + kb2.y * qb2.y + kb2.z * qb2.z + kb2.w * qb2.w;
            lbase[(size_t)slotB * 8 + h] = d * SCALE;
        }
    }
}

// One WAVE (64 lanes) per node; WPB waves per block, fully independent
// (disjoint LDS slices, no s_barrier). R6-verified body; logits are
// CSR-slot-ordered so lane t reads lbase[t*8] -> one contiguous 2KB wave
// segment. Values gathered via eid2. Do NOT hand-unroll the value loop
// (R8/R9 regression) and do NOT load offsets as int2 (4B align).
__global__ void __launch_bounds__(64 * WPB)
node_kernel(const float* __restrict__ logits,    // [N*CAP*8] CSR slots
            const float4* __restrict__ value0,   // [E*8]  float4
            const float4* __restrict__ value1,   // [E*24] float4
            const int* __restrict__ cnt,         // [N]
            const int* __restrict__ eid2,        // [N*CAP]
            float4* __restrict__ out0,           // [N*8]  float4
            float4* __restrict__ out1,           // [N*24] float4
            int N) {
    __shared__ float w_sh[WPB][64][9];           // padded: stride 9 banks

    int wv = threadIdx.x >> 6;
    int t  = threadIdx.x & 63;
    int n  = blockIdx.x * WPB + wv;
    if (n >= N) return;

    const int* eidp = eid2 + (size_t)n * CAP;
    const float* lbase = logits + (size_t)n * CAP * 8;
    int deg = min(cnt[n], CAP);

    if (deg == 0) {
        float4 z = {0.f, 0.f, 0.f, 0.f};
        if (t < 8) out0[(size_t)n * 8 + t] = z;
        else if (t < 32) out1[(size_t)n * 24 + (t - 8)] = z;
        return;
    }

    // chunk-0 logits: lane t -> slot t (32B contiguous, coalesced wave read)
    int myeid = -1;
    float lg[8];
    if (t < deg) {
        myeid = eidp[t];
        const float4* lp = (const float4*)(lbase + (size_t)t * 8);
        float4 a = lp[0], b = lp[1];
        lg[0] = a.x; lg[1] = a.y; lg[2] = a.z; lg[3] = a.w;
        lg[4] = b.x; lg[5] = b.y; lg[6] = b.z; lg[7] = b.w;
    } else {
#pragma unroll
        for (int k = 0; k < 8; ++k) lg[k] = -INFINITY;
    }

    // per-head max (running over rare extra chunks)
    float mx[8];
#pragma unroll
    for (int k = 0; k < 8; ++k) mx[k] = lg[k];
    for (int base = 64; base < deg; base += 64) {       // rare: deg > 64
        if (base + t < deg) {
            const float4* lp = (const float4*)(lbase + (size_t)(base + t) * 8);
            float4 a = lp[0], b = lp[1];
            float tt[8] = {a.x, a.y, a.z, a.w, b.x, b.y, b.z, b.w};
#pragma unroll
            for (int k = 0; k < 8; ++k) mx[k] = fmaxf(mx[k], tt[k]);
        }
    }
#pragma unroll
    for (int k = 0; k < 8; ++k)
        for (int off = 32; off; off >>= 1)
            mx[k] = fmaxf(mx[k], __shfl_xor(mx[k], off, 64));

    // per-head sum of exp (exp(-inf - m) = 0 handles inactive lanes)
    float ex0[8], sm[8];
#pragma unroll
    for (int k = 0; k < 8; ++k) { ex0[k] = __expf(lg[k] - mx[k]); sm[k] = ex0[k]; }
    for (int base = 64; base < deg; base += 64) {       // rare
        if (base + t < deg) {
            const float4* lp = (const float4*)(lbase + (size_t)(base + t) * 8);
            float4 a = lp[0], b = lp[1];
            float tt[8] = {a.x, a.y, a.z, a.w, b.x, b.y, b.z, b.w};
#pragma unroll
            for (int k = 0; k < 8; ++k) sm[k] += __expf(tt[k] - mx[k]);
        }
    }
#pragma unroll
    for (int k = 0; k < 8; ++k)
        for (int off = 32; off; off >>= 1)
            sm[k] += __shfl_xor(sm[k], off, 64);
    float inv[8];
#pragma unroll
    for (int k = 0; k < 8; ++k) inv[k] = 1.0f / sm[k];

    // value accumulation: each 32-lane half owns alternate edges; lane's
    // float4 is a single-head slice (myh) of value0/value1.
    int half = t >> 5;
    int l = t & 31;
    int myh = (l < 8) ? l : ((l - 8) / 3);
    float4 acc = {0.f, 0.f, 0.f, 0.f};

    for (int base = 0; base < deg; base += 64) {
        int clen = min(64, deg - base);
        if (base == 0) {
            if (t < clen) {
#pragma unroll
                for (int k = 0; k < 8; ++k) w_sh[wv][t][k] = ex0[k] * inv[k];
            }
        } else {                                        // rare
            if (base + t < deg) {
                const float4* lp = (const float4*)(lbase + (size_t)(base + t) * 8);
                float4 a = lp[0], b = lp[1];
                float tt[8] = {a.x, a.y, a.z, a.w, b.x, b.y, b.z, b.w};
#pragma unroll
                for (int k = 0; k < 8; ++k)
                    w_sh[wv][t][k] = __expf(tt[k] - mx[k]) * inv[k];
            }
        }
        __builtin_amdgcn_wave_barrier();  // compiler fence: DS pipe is in-order per wave

        for (int ii = half; ii < clen; ii += 2) {
            int e = (base == 0) ? __shfl(myeid, ii, 64)
                                : eidp[base + ii];
            float w = w_sh[wv][ii][myh];
            float4 v = (l < 8) ? value0[(size_t)e * 8 + l]
                               : value1[(size_t)e * 24 + (l - 8)];
            acc.x += w * v.x;
            acc.y += w * v.y;
            acc.z += w * v.z;
            acc.w += w * v.w;
        }
        __builtin_amdgcn_wave_barrier();
    }

    // cross-half reduce, lanes 0-31 store
    acc.x += __shfl_xor(acc.x, 32, 64);
    acc.y += __shfl_xor(acc.y, 32, 64);
    acc.z += __shfl_xor(acc.z, 32, 64);
    acc.w += __shfl_xor(acc.w, 32, 64);
    if (t < 8)       out0[(size_t)n * 8 + l] = acc;
    else if (t < 32) out1[(size_t)n * 24 + (l - 8)] = acc;
}

extern "C" void kernel_launch(void* const* d_in, const int* in_sizes, int n_in,
                              void* d_out, int out_size, void* d_ws, size_t ws_size,
                              hipStream_t stream) {
    const float* key0   = (const float*)d_in[0];
    const float* key1   = (const float*)d_in[1];
    const float* value0 = (const float*)d_in[2];
    const float* value1 = (const float*)d_in[3];
    const float* query0 = (const float*)d_in[4];
    const float* query1 = (const float*)d_in[5];
    const int*   dst    = (const int*)d_in[6];

    int E = in_sizes[0] / CHVAL;   // 500000
    int N = in_sizes[4] / CHVAL;   // 50000

    // workspace layout (4-byte elements):
    //   logits [N*CAP*8] = 409.6 MB (CSR-slot order, only deg slots touched)
    //   cnt    [N]
    //   eid2   [N*CAP]   = 51.2 MB
    float* logits = (float*)d_ws;
    int*   cnt    = (int*)(logits + (size_t)N * CAP * 8);
    int*   eid2   = cnt + N;

    float* out0 = (float*)d_out;             // N*32
    float* out1 = out0 + (size_t)N * 32;     // N*96

    hipMemsetAsync(cnt, 0, (size_t)N * sizeof(int), stream);

    int blk = 256;
    scatter2_kernel<<<(E + blk - 1) / blk, blk, 0, stream>>>(dst, cnt, eid2, E);

    int nnb = (N + WPB - 1) / WPB;
    logits_csr3_kernel<<<nnb, 64 * WPB, 0, stream>>>(
        (const float4*)key0, (const float4*)key1,
        (const float4*)query0, (const float4*)query1,
        cnt, eid2, logits, N);

    node_kernel<<<nnb, 64 * WPB, 0, stream>>>(logits,
                                              (const float4*)value0,
                                              (const float4*)value1,
                                              cnt, eid2,
                                              (float4*)out0, (float4*)out1, N);
}